// Round 9
// baseline (377.079 us; speedup 1.0000x reference)
//
#include <hip/hip_runtime.h>
#include <hip/hip_bf16.h>

#define KK 9
#define PADK 4
#define CIN 64
#define COUT 64
#define LSEQ 131072
#define NB 4
#define TILEL 128         // l-extent of a block tile (>=128B wave row segment, R2 lesson)
#define XROWS 136         // TILEL + KK - 1
#define XRS 72            // xt row stride (bf16); 144 B rows -> uniform 8/bank reads
#define NTILES 1024       // LSEQ / TILEL
#define NPART 64
#define TPB2 4            // tiles per block in async conv
#define GRID2 (NB * NTILES / TPB2)       // 1024 blocks
#define IMGROWB 144                      // xg row bytes (= XRS*2)
#define IMGB 18875520ULL                 // (LSEQ+8)*144 per batch
#define SLABB 18432                      // TILEL*144: slab byte offset per tile
#define SLABSZ 19584                     // XROWS*144: slab bytes (= LDS buffer)

#define AS1 __attribute__((address_space(1)))
#define AS3 __attribute__((address_space(3)))

typedef __attribute__((ext_vector_type(8))) short v8s;
typedef __attribute__((ext_vector_type(4))) float v4f;

__device__ __forceinline__ unsigned short f2bf(float f) {
  __hip_bfloat16 h = __float2bfloat16(f);
  return *reinterpret_cast<unsigned short*>(&h);
}
__device__ __forceinline__ float bf2f(unsigned short s) {
  return __uint_as_float(((unsigned)s) << 16);
}

__device__ __forceinline__ void store_o(float* p, float v) { *p = v; }
__device__ __forceinline__ void store_o(__hip_bfloat16* p, float v) { *p = __float2bfloat16(v); }

__device__ __forceinline__ void gl_lds16(const void* g, void* l) {
  __builtin_amdgcn_global_load_lds((const AS1 unsigned int*)g,
                                   (AS3 unsigned int*)l, 16, 0, 0);
}

// 16-lane (intra-row) sum on the VALU pipe via DPP (verified R2/R4/R6)
template <int CTRL>
__device__ __forceinline__ float dppadd(float v) {
  int s = __builtin_amdgcn_update_dpp(0, __float_as_int(v), CTRL, 0xF, 0xF, true);
  return v + __int_as_float(s);
}
__device__ __forceinline__ float red16(float v) {
  v = dppadd<0xB1>(v);
  v = dppadd<0x4E>(v);
  v = dppadd<0x141>(v);
  v = dppadd<0x140>(v);
  return v;
}

// ---------------------------------------------------------------------------
// Repack W[Cout][Cin][K] fp32 -> bf16 A-fragments for mfma_f32_16x16x32_bf16.
// ---------------------------------------------------------------------------
__global__ void wtrans_kernel(const float* __restrict__ W, v8s* __restrict__ Wt) {
  int t = blockIdx.x * 256 + threadIdx.x;
  if (t >= KK * 2 * 4 * 64) return;
  int lane = t & 63;
  int frag = t >> 6;
  int mblk = frag & 3;
  int s    = (frag >> 2) & 1;
  int k    = frag >> 3;
  int m = lane & 15, q = lane >> 4;
  int o = mblk * 16 + m;
  union { v8s v; unsigned short h[8]; } u;
#pragma unroll
  for (int j = 0; j < 8; ++j) {
    int c = 32 * s + q * 8 + j;
    u.h[j] = f2bf(W[(o * CIN + c) * KK + k]);
  }
  Wt[t] = u.v;
}

// ---------------------------------------------------------------------------
// R9 xtrans: x f32 [C][L] -> xg bf16 transposed padded image, per batch:
// rows = l+4 (4 zero halo rows each end), row stride 144 B, cols = channel*2B.
// Layout EXACTLY matches the conv LDS tile, so conv stages via a linear
// global_load_lds byte copy (slab offset tile*18432, length 19584).
// ---------------------------------------------------------------------------
__global__ __launch_bounds__(256)
void xtrans_kernel(const float* __restrict__ x, char* __restrict__ xg) {
  const int blk = blockIdx.x;           // 0..4095
  const int b = blk >> 10;
  const int t = blk & (NTILES - 1);
  const int l0 = t * TILEL;
  const int tid = threadIdx.x;
  const float* xb = x + (size_t)(b * CIN) * LSEQ;
  char* xgb = xg + (size_t)b * IMGB;

  const int cg = tid & 7, lc = tid >> 3, c8 = cg * 8;
  float4 f[8];
#pragma unroll
  for (int tt = 0; tt < 8; ++tt)
    f[tt] = *(const float4*)(xb + (c8 + tt) * LSEQ + l0 + 4 * lc);
  const float* fp = (const float*)&f[0];
#pragma unroll
  for (int j = 0; j < 4; ++j) {
    union { v8s v; unsigned short h[8]; } u;
#pragma unroll
    for (int tt = 0; tt < 8; ++tt) u.h[tt] = f2bf(fp[4 * tt + j]);
    *(v8s*)(xgb + (size_t)(l0 + 4 * lc + j + 4) * IMGROWB + c8 * 2) = u.v;
  }
  // zero halo rows (4 rows x 144 B = 576 B = 36 x 16 B each end)
  if (t == 0 && tid < 36)
    *(float4*)(xgb + tid * 16) = make_float4(0.f, 0.f, 0.f, 0.f);
  if (t == NTILES - 1 && tid < 36)
    *(float4*)(xgb + (size_t)131076 * IMGROWB + tid * 16) = make_float4(0.f, 0.f, 0.f, 0.f);
}

// ---------------------------------------------------------------------------
// R9 conv_async: staging via global_load_lds (register-free, conversion-free)
// with double-buffered LDS and TPB2=4 tiles per block. Per iteration:
//   MFMA(cur) [vmcnt queue empty -> Wt frag waits don't drain the pipeline]
//   -> issue coords(t+1) + 20x gl_lds -> xt[cur^1]
//   -> epilogue stores(t) -> wt exp-compute(t+1) -> __syncthreads()
// The gl_lds batch is in flight across epilogue+wt (~800cy) before the drain.
// Regs: R6 body 72 unified + ~18 coord regs <= 102 -> 5-wave cap intact.
// ---------------------------------------------------------------------------
template <typename OutT>
__global__ __launch_bounds__(256, 5)
void conv_async(const char* __restrict__ xg, const float* __restrict__ coords,
                const v8s* __restrict__ Wt, OutT* __restrict__ cv,
                float* __restrict__ stat_sum, float* __restrict__ stat_sq) {
  __shared__ __align__(16) __hip_bfloat16 xt[2][XROWS][XRS]; // 39168 B
  __shared__ float wt[2][KK][TILEL];                         //  9216 B

  const int tid  = threadIdx.x;
  const int wv   = tid >> 6;
  const int wo   = wv & 1;
  const int wl   = wv >> 1;
  const int lane = tid & 63;
  const int m = lane & 15;
  const int q = lane >> 4;

  const int bid = blockIdx.x;                 // 0..1023
  const int b   = bid >> 8;                   // 256 blocks per batch
  const int t0  = (bid & 255) * TPB2;
  const char* xgb = xg + (size_t)b * IMGB;
  const float* cb = coords + (size_t)(b * 3) * LSEQ;
  OutT* outb = cv + (size_t)(b * COUT) * LSEQ;

  // coord roles: kh=0 -> k 0..3, kh=1 -> k 4..8
  const int cn = tid & 127, kh = tid >> 7, k0 = kh * 4;
  const int nk = kh ? 5 : 4;

  float sx, sy, sz;
  float nx[5], ny[5], nz[5];

  auto coord_issue = [&](int tile) {
    const int l0 = tile * TILEL;
    sx = cb[l0 + cn];
    sy = cb[LSEQ + l0 + cn];
    sz = cb[2 * LSEQ + l0 + cn];
#pragma unroll
    for (int i = 0; i < 5; ++i) {
      int l = l0 + cn + (k0 + i) - PADK;
      float cx = 0.f, cy = 0.f, cz = 0.f;
      if (i < nk && (unsigned)l < (unsigned)LSEQ) {   // zero-pad like jnp.pad
        cx = cb[l]; cy = cb[LSEQ + l]; cz = cb[2 * LSEQ + l];
      }
      nx[i] = cx; ny[i] = cy; nz[i] = cz;
    }
  };

  // linear slab copy: 19584 B; per wave 4896 B = 4 full rounds + 50 lanes
  auto stage = [&](int tile, int nxt) {
    const char* src = xgb + (size_t)tile * SLABB + wv * 4896;
    char* dst = (char*)&xt[nxt][0][0] + wv * 4896;
#pragma unroll
    for (int j = 0; j < 4; ++j)
      gl_lds16(src + j * 1024 + lane * 16, dst + j * 1024);
    if (lane < 50)
      gl_lds16(src + 4096 + lane * 16, dst + 4096);
  };

  auto wt_write = [&](int nxt) {
#pragma unroll
    for (int i = 0; i < 5; ++i) {
      if (i < nk) {
        float dx = nx[i] - sx, dy = ny[i] - sy, dz = nz[i] - sz;
        wt[nxt][k0 + i][cn] = __expf(-0.5f * (dx * dx + dy * dy + dz * dz));
      }
    }
  };

  // ---- prologue: tile t0 into buffer 0 ----
  coord_issue(t0);
  stage(t0, 0);
  wt_write(0);            // waits coords only (gl_lds newer in queue stays put)
  __syncthreads();        // vmcnt(0)+lgkm drain + barrier: xt[0]/wt[0] ready

#pragma unroll 1
  for (int ti = 0; ti < TPB2; ++ti) {
    const int tile = t0 + ti;
    const int l0 = tile * TILEL;
    const int cur = ti & 1;

    // ---- MFMA: direct per-k weighted accumulation (R6 body) ----
    v4f tot[2][4];
#pragma unroll
    for (int i = 0; i < 2; ++i)
#pragma unroll
      for (int j = 0; j < 4; ++j)
        tot[i][j] = (v4f){0.f, 0.f, 0.f, 0.f};

    const v4f z4 = (v4f){0.f, 0.f, 0.f, 0.f};
    const v8s* wp = Wt + (wo * 2) * 64 + lane;

#pragma unroll 1
    for (int k = 0; k < KK; ++k) {
      v8s a00 = wp[k * 512];
      v8s a10 = wp[k * 512 + 64];
      v8s a01 = wp[k * 512 + 256];
      v8s a11 = wp[k * 512 + 320];
#pragma unroll
      for (int nbq = 0; nbq < 4; ++nbq) {
        const __hip_bfloat16* xr = &xt[cur][wl * 64 + nbq * 16 + m + k][0];
        v8s bf0 = *(const v8s*)(xr + q * 8);
        v8s bf1 = *(const v8s*)(xr + q * 8 + 32);
        float wk = wt[cur][k][wl * 64 + nbq * 16 + m];
        v4f y0 = __builtin_amdgcn_mfma_f32_16x16x32_bf16(a00, bf0, z4, 0, 0, 0);
        y0     = __builtin_amdgcn_mfma_f32_16x16x32_bf16(a01, bf1, y0, 0, 0, 0);
        v4f y1 = __builtin_amdgcn_mfma_f32_16x16x32_bf16(a10, bf0, z4, 0, 0, 0);
        y1     = __builtin_amdgcn_mfma_f32_16x16x32_bf16(a11, bf1, y1, 0, 0, 0);
#pragma unroll
        for (int r = 0; r < 4; ++r) {
          tot[0][nbq][r] = __builtin_fmaf(wk, y0[r], tot[0][nbq][r]);
          tot[1][nbq][r] = __builtin_fmaf(wk, y1[r], tot[1][nbq][r]);
        }
      }
    }

    // ---- issue next tile's coords + async LDS stage (in flight from here) ----
    if (ti + 1 < TPB2) {
      coord_issue(tile + 1);
      stage(tile + 1, cur ^ 1);
    }

    // ---- epilogue: store conv result + per-channel sum/sumsq partials ----
    const int part = tile & (NPART - 1);
#pragma unroll
    for (int mb = 0; mb < 2; ++mb) {
#pragma unroll
      for (int r = 0; r < 4; ++r) {
        int o = wo * 32 + mb * 16 + q * 4 + r;
        float s1 = 0.f, s2 = 0.f;
#pragma unroll
        for (int nbq = 0; nbq < 4; ++nbq) {
          float v = tot[mb][nbq][r];
          s1 += v;
          s2 += v * v;
          store_o(&outb[o * LSEQ + l0 + wl * 64 + nbq * 16 + m], v);
        }
        s1 = red16(s1);
        s2 = red16(s2);
        if (m == 0) {
          atomicAdd(&stat_sum[part * COUT + o], s1);
          atomicAdd(&stat_sq [part * COUT + o], s2);
        }
      }
    }

    // ---- gaussian weights for t+1 (coords have landed under the epilogue) ----
    if (ti + 1 < TPB2) wt_write(cur ^ 1);

    __syncthreads();   // drains gl_lds (issued ~epilogue ago) + protects buffers
  }
}

// ---------------------------------------------------------------------------
// R6 fallback conv (workspace too small for xg image).
// ---------------------------------------------------------------------------
template <typename OutT>
__global__ __launch_bounds__(256, 5)
void conv_fallback(const float* __restrict__ x, const float* __restrict__ coords,
                   const v8s* __restrict__ Wt, OutT* __restrict__ cv,
                   float* __restrict__ stat_sum, float* __restrict__ stat_sq) {
  __shared__ __align__(16) __hip_bfloat16 xt[XROWS][XRS];
  __shared__ float wt[KK][TILEL];

  const int tid  = threadIdx.x;
  const int wv   = tid >> 6;
  const int wo   = wv & 1;
  const int wl   = wv >> 1;
  const int lane = tid & 63;
  const int gw   = blockIdx.x;
  const int b    = gw >> 10;
  const int tile = gw & (NTILES - 1);
  const int l0   = tile * TILEL;
  const float* xb = x + (size_t)(b * CIN) * LSEQ;
  const float* cb = coords + (size_t)(b * 3) * LSEQ;
  const int m = lane & 15;
  const int q = lane >> 4;

  {
    int cg = tid & 7;
    int lc = tid >> 3;
    int c8 = cg * 8;
    float4 f[8];
#pragma unroll
    for (int t = 0; t < 8; ++t)
      f[t] = *(const float4*)(xb + (c8 + t) * LSEQ + l0 + 4 * lc);
    const float* fp = (const float*)&f[0];
#pragma unroll
    for (int j = 0; j < 4; ++j) {
      union { v8s v; unsigned short h[8]; } u;
#pragma unroll
      for (int t = 0; t < 8; ++t) u.h[t] = f2bf(fp[4 * t + j]);
      *(v8s*)&xt[4 + 4 * lc + j][c8] = u.v;
    }
  }
  if (tid < 128) {
    int side = tid >> 6;
    int c = tid & 63;
    if (side == 0) {
      float el[4] = {0.f, 0.f, 0.f, 0.f};
      if (tile != 0) {
#pragma unroll
        for (int j = 0; j < 4; ++j) el[j] = xb[c * LSEQ + l0 - 4 + j];
      }
#pragma unroll
      for (int j = 0; j < 4; ++j) xt[j][c] = __float2bfloat16(el[j]);
    } else {
      float er[4] = {0.f, 0.f, 0.f, 0.f};
      if (tile != NTILES - 1) {
#pragma unroll
        for (int j = 0; j < 4; ++j) er[j] = xb[c * LSEQ + l0 + TILEL + j];
      }
#pragma unroll
      for (int j = 0; j < 4; ++j) xt[128 + 4 + j][c] = __float2bfloat16(er[j]);
    }
  }
  if (tid < TILEL) {
    int n = tid;
    float sx = cb[l0 + n];
    float sy = cb[LSEQ + l0 + n];
    float sz = cb[2 * LSEQ + l0 + n];
#pragma unroll
    for (int k = 0; k < KK; ++k) {
      int l = l0 + n + k - PADK;
      float cx = 0.f, cy = 0.f, cz = 0.f;
      if ((unsigned)l < (unsigned)LSEQ) {
        cx = cb[l]; cy = cb[LSEQ + l]; cz = cb[2 * LSEQ + l];
      }
      float dx = cx - sx, dy = cy - sy, dz = cz - sz;
      wt[k][n] = __expf(-0.5f * (dx * dx + dy * dy + dz * dz));
    }
  }
  __syncthreads();

  v4f tot[2][4];
#pragma unroll
  for (int i = 0; i < 2; ++i)
#pragma unroll
    for (int j = 0; j < 4; ++j)
      tot[i][j] = (v4f){0.f, 0.f, 0.f, 0.f};

  const v4f z4 = (v4f){0.f, 0.f, 0.f, 0.f};
  const v8s* wp = Wt + (wo * 2) * 64 + lane;

#pragma unroll 1
  for (int k = 0; k < KK; ++k) {
    v8s a00 = wp[k * 512];
    v8s a10 = wp[k * 512 + 64];
    v8s a01 = wp[k * 512 + 256];
    v8s a11 = wp[k * 512 + 320];
#pragma unroll
    for (int nbq = 0; nbq < 4; ++nbq) {
      const __hip_bfloat16* xr = &xt[wl * 64 + nbq * 16 + m + k][0];
      v8s bf0 = *(const v8s*)(xr + q * 8);
      v8s bf1 = *(const v8s*)(xr + q * 8 + 32);
      float wk = wt[k][wl * 64 + nbq * 16 + m];
      v4f y0 = __builtin_amdgcn_mfma_f32_16x16x32_bf16(a00, bf0, z4, 0, 0, 0);
      y0     = __builtin_amdgcn_mfma_f32_16x16x32_bf16(a01, bf1, y0, 0, 0, 0);
      v4f y1 = __builtin_amdgcn_mfma_f32_16x16x32_bf16(a10, bf0, z4, 0, 0, 0);
      y1     = __builtin_amdgcn_mfma_f32_16x16x32_bf16(a11, bf1, y1, 0, 0, 0);
#pragma unroll
      for (int r = 0; r < 4; ++r) {
        tot[0][nbq][r] = __builtin_fmaf(wk, y0[r], tot[0][nbq][r]);
        tot[1][nbq][r] = __builtin_fmaf(wk, y1[r], tot[1][nbq][r]);
      }
    }
  }

  const int part = gw & (NPART - 1);
  OutT* outb = cv + (size_t)(b * COUT) * LSEQ;
#pragma unroll
  for (int mb = 0; mb < 2; ++mb) {
#pragma unroll
    for (int r = 0; r < 4; ++r) {
      int o = wo * 32 + mb * 16 + q * 4 + r;
      float s1 = 0.f, s2 = 0.f;
#pragma unroll
      for (int nbq = 0; nbq < 4; ++nbq) {
        float v = tot[mb][nbq][r];
        s1 += v;
        s2 += v * v;
        store_o(&outb[o * LSEQ + l0 + wl * 64 + nbq * 16 + m], v);
      }
      s1 = red16(s1);
      s2 = red16(s2);
      if (m == 0) {
        atomicAdd(&stat_sum[part * COUT + o], s1);
        atomicAdd(&stat_sq [part * COUT + o], s2);
      }
    }
  }
}

// ---------------------------------------------------------------------------
// BN finalize (256 threads) + BN/ReLU apply kernels.
// ---------------------------------------------------------------------------
__global__ __launch_bounds__(256)
void finalize_kernel(const float* __restrict__ stat_sum,
                     const float* __restrict__ stat_sq,
                     const float* __restrict__ gamma,
                     const float* __restrict__ beta,
                     float* __restrict__ ss) {
  __shared__ float red[2][4][COUT];
  const int o = threadIdx.x & 63, pq = threadIdx.x >> 6;
  float s1 = 0.f, s2 = 0.f;
#pragma unroll 4
  for (int p = pq * 16; p < pq * 16 + 16; ++p) {
    s1 += stat_sum[p * COUT + o];
    s2 += stat_sq [p * COUT + o];
  }
  red[0][pq][o] = s1;
  red[1][pq][o] = s2;
  __syncthreads();
  if (threadIdx.x < 64) {
    float t1 = red[0][0][o] + red[0][1][o] + red[0][2][o] + red[0][3][o];
    float t2 = red[1][0][o] + red[1][1][o] + red[1][2][o] + red[1][3][o];
    const float invN = 1.0f / (float)(NB * LSEQ);
    float mean = t1 * invN;
    float var  = t2 * invN - mean * mean;   // biased, matches jnp.var
    float sc = gamma[o] * rsqrtf(var + 1e-5f);
    ss[o]        = sc;
    ss[COUT + o] = beta[o] - mean * sc;
  }
}

__global__ __launch_bounds__(256)
void scale_f32_kernel(float* __restrict__ data, const float* __restrict__ ss) {
  const int blk = blockIdx.x;
  const int ch = (blk >> 6) & 63;
  const float sc = ss[ch];
  const float sh = ss[COUT + ch];
  const int base = blk * 2048 + threadIdx.x * 8;
  float4 a = *(float4*)(data + base);
  float4 b = *(float4*)(data + base + 4);
  a.x = fmaxf(fmaf(a.x, sc, sh), 0.f);
  a.y = fmaxf(fmaf(a.y, sc, sh), 0.f);
  a.z = fmaxf(fmaf(a.z, sc, sh), 0.f);
  a.w = fmaxf(fmaf(a.w, sc, sh), 0.f);
  b.x = fmaxf(fmaf(b.x, sc, sh), 0.f);
  b.y = fmaxf(fmaf(b.y, sc, sh), 0.f);
  b.z = fmaxf(fmaf(b.z, sc, sh), 0.f);
  b.w = fmaxf(fmaf(b.w, sc, sh), 0.f);
  *(float4*)(data + base)     = a;
  *(float4*)(data + base + 4) = b;
}

__global__ __launch_bounds__(256)
void scale_bf16_kernel(const __hip_bfloat16* __restrict__ cvin,
                       const float* __restrict__ ss, float* __restrict__ out) {
  const int blk = blockIdx.x;
  const int ch = (blk >> 6) & 63;
  const float sc = ss[ch];
  const float sh = ss[COUT + ch];
  const int base = blk * 2048 + threadIdx.x * 8;
  union { v8s v; unsigned short h[8]; } u;
  u.v = *(const v8s*)(cvin + base);
  float r[8];
#pragma unroll
  for (int i = 0; i < 8; ++i)
    r[i] = fmaxf(fmaf(bf2f(u.h[i]), sc, sh), 0.f);
  *(float4*)(out + base)     = make_float4(r[0], r[1], r[2], r[3]);
  *(float4*)(out + base + 4) = make_float4(r[4], r[5], r[6], r[7]);
}

extern "C" void kernel_launch(void* const* d_in, const int* in_sizes, int n_in,
                              void* d_out, int out_size, void* d_ws, size_t ws_size,
                              hipStream_t stream) {
  const float* x      = (const float*)d_in[0];
  const float* coords = (const float*)d_in[1];
  const float* W      = (const float*)d_in[2];
  // d_in[3] = bias: cancels under training-mode BatchNorm; unused.
  const float* gamma  = (const float*)d_in[4];
  const float* beta   = (const float*)d_in[5];
  float* out = (float*)d_out;
  char* ws = (char*)d_ws;

  float* stat_sum = (float*)(ws);            // 64*64 f32
  float* stat_sq  = (float*)(ws + 16384);
  float* ss       = (float*)(ws + 32768);    // 128 f32
  v8s*   Wt       = (v8s*)(ws + 40960);      // 73728 B

  char*  xg       = ws + 131072;                       // 4*IMGB = 75502080 B
  const size_t xg_end    = 131072ULL + 4ULL * IMGB;    // 75633152
  const size_t scr_bytes = (size_t)NB * COUT * LSEQ * 2;  // 67108864

  const size_t need_full = xg_end + scr_bytes;         // xtrans + bf16 scratch
  const size_t need_xg   = xg_end;                     // xtrans + f32 direct
  const size_t need_old  = 131072ULL + scr_bytes;      // R6 bf16 path

  hipMemsetAsync(ws, 0, 32768, stream);
  wtrans_kernel<<<18, 256, 0, stream>>>(W, Wt);

  if (ws_size >= need_full) {
    __hip_bfloat16* scratch = (__hip_bfloat16*)(ws + xg_end);
    xtrans_kernel<<<NB * NTILES, 256, 0, stream>>>(x, xg);
    conv_async<__hip_bfloat16><<<GRID2, 256, 0, stream>>>(
        xg, coords, Wt, scratch, stat_sum, stat_sq);
    finalize_kernel<<<1, 256, 0, stream>>>(stat_sum, stat_sq, gamma, beta, ss);
    scale_bf16_kernel<<<(NB * COUT * (LSEQ / 2048)), 256, 0, stream>>>(scratch, ss, out);
  } else if (ws_size >= need_xg) {
    xtrans_kernel<<<NB * NTILES, 256, 0, stream>>>(x, xg);
    conv_async<float><<<GRID2, 256, 0, stream>>>(
        xg, coords, Wt, out, stat_sum, stat_sq);
    finalize_kernel<<<1, 256, 0, stream>>>(stat_sum, stat_sq, gamma, beta, ss);
    scale_f32_kernel<<<(NB * COUT * (LSEQ / 2048)), 256, 0, stream>>>(out, ss);
  } else if (ws_size >= need_old) {
    __hip_bfloat16* scratch = (__hip_bfloat16*)(ws + 131072);
    conv_fallback<__hip_bfloat16><<<NB * NTILES, 256, 0, stream>>>(
        x, coords, Wt, scratch, stat_sum, stat_sq);
    finalize_kernel<<<1, 256, 0, stream>>>(stat_sum, stat_sq, gamma, beta, ss);
    scale_bf16_kernel<<<(NB * COUT * (LSEQ / 2048)), 256, 0, stream>>>(scratch, ss, out);
  } else {
    conv_fallback<float><<<NB * NTILES, 256, 0, stream>>>(
        x, coords, Wt, out, stat_sum, stat_sq);
    finalize_kernel<<<1, 256, 0, stream>>>(stat_sum, stat_sq, gamma, beta, ss);
    scale_f32_kernel<<<(NB * COUT * (LSEQ / 2048)), 256, 0, stream>>>(out, ss);
  }
}